// Round 5
// baseline (2569.901 us; speedup 1.0000x reference)
//
#include <hip/hip_runtime.h>

#define USER_NUM 100000
#define ITEM_NUM 50000
#define NTOT     (USER_NUM + ITEM_NUM)
#define EMB      64
#define GAMMA    0.5f
#define NLAYERS  3
#define EPS      1e-12f

#define SCAN_CHUNK 256
#define NCHUNKS    ((NTOT + SCAN_CHUNK - 1) / SCAN_CHUNK)   // 586

// superbin partition parameters
#define SB_SHIFT 9
#define SB_ROWS  (1 << SB_SHIFT)                             // 512 rows / superbin
#define NSB      ((NTOT + SB_ROWS - 1) >> SB_SHIFT)          // 293
#define PCAP     24                                          // records buffered per bin
#define PCHUNK   1024                                        // records per block-chunk
#define PBLOCKS  512                                         // 2 blocks/CU (LDS-limited)
#define COLBITS  18                                          // cols < 150000 < 2^18
#define COLMASK  ((1 << COLBITS) - 1)

// ---- bf16 helpers (explicit RNE, bit-level) ----
__device__ __forceinline__ unsigned short f2bf(float f) {
    unsigned u = __float_as_uint(f);
    u = (u + 0x7FFFu + ((u >> 16) & 1u)) >> 16;
    return (unsigned short)u;
}
__device__ __forceinline__ float bf2f(unsigned short h) {
    return __uint_as_float((unsigned)h << 16);
}

// ===========================================================================
// init: Xh = bf16(normalize(concat(user,item))), out = GAMMA * concat(...)
// ===========================================================================
__global__ void init_kernel(const float* __restrict__ user_emb,
                            const float* __restrict__ item_emb,
                            unsigned short* __restrict__ Xh,
                            float* __restrict__ out) {
    int tid = blockIdx.x * blockDim.x + threadIdx.x;
    int row = tid >> 4;
    if (row >= NTOT) return;
    int l = tid & 15;
    const float* src = (row < USER_NUM)
        ? user_emb + (size_t)row * EMB
        : item_emb + (size_t)(row - USER_NUM) * EMB;
    float4 v = reinterpret_cast<const float4*>(src)[l];
    float4 o = v; o.x *= GAMMA; o.y *= GAMMA; o.z *= GAMMA; o.w *= GAMMA;
    reinterpret_cast<float4*>(out)[(size_t)row * 16 + l] = o;
    float ss = v.x * v.x + v.y * v.y + v.z * v.z + v.w * v.w;
    ss += __shfl_xor(ss, 1);
    ss += __shfl_xor(ss, 2);
    ss += __shfl_xor(ss, 4);
    ss += __shfl_xor(ss, 8);
    float inv = 1.0f / (sqrtf(ss) + EPS);
    ushort4 h;
    h.x = f2bf(v.x * inv); h.y = f2bf(v.y * inv);
    h.z = f2bf(v.z * inv); h.w = f2bf(v.w * inv);
    reinterpret_cast<ushort4*>(Xh)[(size_t)row * 16 + l] = h;
}

// ===========================================================================
// histogram (int4-vectorized index reads)
// ===========================================================================
__global__ void hist4_kernel(const int* __restrict__ rows,
                             int* __restrict__ counts, int nnz) {
    int tid = blockIdx.x * blockDim.x + threadIdx.x;
    int stride = gridDim.x * blockDim.x;
    int nnz4 = nnz >> 2;
    for (int i = tid; i < nnz4; i += stride) {
        int4 r4 = reinterpret_cast<const int4*>(rows)[i];
        atomicAdd(&counts[r4.x], 1);
        atomicAdd(&counts[r4.y], 1);
        atomicAdd(&counts[r4.z], 1);
        atomicAdd(&counts[r4.w], 1);
    }
    if (tid == 0)
        for (int i = nnz4 << 2; i < nnz; ++i) atomicAdd(&counts[rows[i]], 1);
}

// ===========================================================================
// 3-step exclusive scan of per-row counts -> row_ptr (and cursor copy)
// ===========================================================================
__global__ void scan_sums_kernel(const int* __restrict__ counts,
                                 int* __restrict__ chunk_sums) {
    __shared__ int sdata[SCAN_CHUNK];
    int idx = blockIdx.x * SCAN_CHUNK + threadIdx.x;
    int v = (idx < NTOT) ? counts[idx] : 0;
    sdata[threadIdx.x] = v;
    __syncthreads();
    for (int off = SCAN_CHUNK / 2; off > 0; off >>= 1) {
        if (threadIdx.x < off) sdata[threadIdx.x] += sdata[threadIdx.x + off];
        __syncthreads();
    }
    if (threadIdx.x == 0) chunk_sums[blockIdx.x] = sdata[0];
}

__global__ void scan_offsets_kernel(int* __restrict__ chunk_sums,
                                    int* __restrict__ row_ptr) {
    if (threadIdx.x == 0 && blockIdx.x == 0) {
        int running = 0;
        for (int b = 0; b < NCHUNKS; ++b) {
            int t = chunk_sums[b];
            chunk_sums[b] = running;
            running += t;
        }
        row_ptr[NTOT] = running;
    }
}

__global__ void scan_write_kernel(const int* __restrict__ counts,
                                  const int* __restrict__ chunk_sums,
                                  int* __restrict__ row_ptr,
                                  int* __restrict__ cursor) {
    __shared__ int temp[SCAN_CHUNK];
    int idx = blockIdx.x * SCAN_CHUNK + threadIdx.x;
    int v = (idx < NTOT) ? counts[idx] : 0;
    temp[threadIdx.x] = v;
    __syncthreads();
    for (int off = 1; off < SCAN_CHUNK; off <<= 1) {
        int t = (threadIdx.x >= off) ? temp[threadIdx.x - off] : 0;
        __syncthreads();
        temp[threadIdx.x] += t;
        __syncthreads();
    }
    if (idx < NTOT) {
        int excl = temp[threadIdx.x] - v + chunk_sums[blockIdx.x];
        row_ptr[idx] = excl;
        cursor[idx]  = excl;
    }
}

// ===========================================================================
// superbin counts (segment sums of row counts) + tiny scan (8-record-aligned
// bases so every full flush in the partition kernel is 64B-line-aligned)
// ===========================================================================
__global__ void sbcount_kernel(const int* __restrict__ counts,
                               int* __restrict__ sb_count) {
    int sb = blockIdx.x;
    int lane = threadIdx.x;                 // 64 threads = 1 wave
    int r0 = sb << SB_SHIFT;
    int r1 = r0 + SB_ROWS; if (r1 > NTOT) r1 = NTOT;
    int s = 0;
    for (int r = r0 + lane; r < r1; r += 64) s += counts[r];
    for (int off = 32; off > 0; off >>= 1) s += __shfl_down(s, off);
    if (lane == 0) sb_count[sb] = s;
}

__global__ void sbscan_kernel(const int* __restrict__ sb_count,
                              int* __restrict__ sb_base,
                              int* __restrict__ sb_cursor) {
    if (threadIdx.x == 0 && blockIdx.x == 0) {
        int run = 0;
        for (int b = 0; b < NSB; ++b) {
            sb_base[b]   = run;
            sb_cursor[b] = run;
            run = (run + sb_count[b] + 7) & ~7;   // keep bases 8-record aligned
        }
    }
}

// ===========================================================================
// Pass 1: LDS-buffered partition into NSB superbins. Bins are flushed in
// multiples of 8 records (= one 64B line) reserved via atomicAdd on the bin
// cursor -> every full flush owns whole lines (no cross-CU line sharing,
// no write amplification). Deadlock-free claim/flush/retry loop; leftover
// (<8) records drained at block end (rare sub-line writes).
// ===========================================================================
__global__ __launch_bounds__(256)
void partition_kernel(const int* __restrict__ rows,
                      const int* __restrict__ cols,
                      const float* __restrict__ vals,
                      int* __restrict__ sb_cursor,
                      int2* __restrict__ staging, int nnz) {
    __shared__ int2 buf[NSB][PCAP];     // 293*24*8 = 56.3 KB
    __shared__ int  fill[NSB];
    __shared__ int  npend;
    const int tid  = threadIdx.x;
    const int wid  = tid >> 6;
    const int lane = tid & 63;

    for (int i = tid; i < NSB; i += 256) fill[i] = 0;
    __syncthreads();

    const int nchunks = (nnz + PCHUNK - 1) / PCHUNK;
    for (int ch = blockIdx.x; ch < nchunks; ch += gridDim.x) {
        int base = ch * PCHUNK + tid * 4;
        int2 rec[4]; int bin[4]; int pmask = 0;
        if (base + 3 < nnz) {
            int4   r4 = *reinterpret_cast<const int4*>(rows + base);
            int4   c4 = *reinterpret_cast<const int4*>(cols + base);
            float4 v4 = *reinterpret_cast<const float4*>(vals + base);
            int   rr[4] = {r4.x, r4.y, r4.z, r4.w};
            int   cc[4] = {c4.x, c4.y, c4.z, c4.w};
            float vv[4] = {v4.x, v4.y, v4.z, v4.w};
#pragma unroll
            for (int j = 0; j < 4; ++j) {
                bin[j] = rr[j] >> SB_SHIFT;
                rec[j] = make_int2(((rr[j] & (SB_ROWS - 1)) << COLBITS) | cc[j],
                                   __float_as_int(vv[j]));
            }
            pmask = 0xF;
        } else {
#pragma unroll
            for (int j = 0; j < 4; ++j) {
                int i = base + j;
                if (i < nnz) {
                    int r = rows[i];
                    bin[j] = r >> SB_SHIFT;
                    rec[j] = make_int2(((r & (SB_ROWS - 1)) << COLBITS) | cols[i],
                                       __float_as_int(vals[i]));
                    pmask |= 1 << j;
                }
            }
        }
        while (true) {
            if (tid == 0) npend = 0;
            __syncthreads();
            // claim phase
#pragma unroll
            for (int j = 0; j < 4; ++j) {
                if (pmask & (1 << j)) {
                    int s = atomicAdd(&fill[bin[j]], 1);
                    if (s < PCAP) { buf[bin[j]][s] = rec[j]; pmask &= ~(1 << j); }
                    else          { atomicSub(&fill[bin[j]], 1); }
                }
            }
            if (pmask) atomicAdd(&npend, 1);
            __syncthreads();
            // flush phase: one wave per bin group; 8-record (64B) granular
            for (int b = wid; b < NSB; b += 4) {
                int f  = fill[b];
                int k8 = f & ~7;
                if (k8) {
                    int gbase = 0;
                    if (lane == 0) gbase = atomicAdd(&sb_cursor[b], k8);
                    gbase = __shfl(gbase, 0);
                    if (lane < k8) staging[gbase + lane] = buf[b][lane];
                    int rem = f - k8;
                    if (lane < rem) {            // move leftovers to front
                        int2 t = buf[b][k8 + lane];
                        buf[b][lane] = t;
                    }
                    if (lane == 0) fill[b] = rem;
                }
            }
            __syncthreads();
            if (npend == 0) break;
        }
    }
    // drain leftovers (< 8 records/bin, once per block)
    for (int b = wid; b < NSB; b += 4) {
        int f = fill[b];
        if (f > 0) {
            int gbase = 0;
            if (lane == 0) gbase = atomicAdd(&sb_cursor[b], f);
            gbase = __shfl(gbase, 0);
            if (lane < f) staging[gbase + lane] = buf[b][lane];
        }
    }
}

// ===========================================================================
// Pass 2: one block per superbin; sequential read of its staging slice,
// row-cursor scatter into the bin's ~218 KB cv window (L2-local).
// ===========================================================================
__global__ void sbfix_kernel(const int2* __restrict__ staging,
                             const int* __restrict__ sb_base,
                             const int* __restrict__ sb_cursor,
                             int* __restrict__ rowcur,
                             int2* __restrict__ cv) {
    int sb = blockIdx.x;
    int s0 = sb_base[sb];
    int s1 = sb_cursor[sb];
    int rbase = sb << SB_SHIFT;
    for (int j = s0 + threadIdx.x; j < s1; j += blockDim.x) {
        int2 rec = staging[j];
        int r   = rbase + (int)((unsigned)rec.x >> COLBITS);
        int pos = atomicAdd(&rowcur[r], 1);
        cv[pos] = make_int2(rec.x & COLMASK, rec.y);
    }
}

// legacy single-pass build (fallback path)
__global__ void build_kernel(const int* __restrict__ rows,
                             const int* __restrict__ cols,
                             const float* __restrict__ vals,
                             int* __restrict__ cursor,
                             int2* __restrict__ cv, int nnz) {
    int tid = blockIdx.x * blockDim.x + threadIdx.x;
    int stride = gridDim.x * blockDim.x;
    int nnz4 = nnz >> 2;
    for (int i = tid; i < nnz4; i += stride) {
        int4   r4 = reinterpret_cast<const int4*>(rows)[i];
        int4   c4 = reinterpret_cast<const int4*>(cols)[i];
        float4 v4 = reinterpret_cast<const float4*>(vals)[i];
        int p0 = atomicAdd(&cursor[r4.x], 1);
        cv[p0] = make_int2(c4.x, __float_as_int(v4.x));
        int p1 = atomicAdd(&cursor[r4.y], 1);
        cv[p1] = make_int2(c4.y, __float_as_int(v4.y));
        int p2 = atomicAdd(&cursor[r4.z], 1);
        cv[p2] = make_int2(c4.z, __float_as_int(v4.z));
        int p3 = atomicAdd(&cursor[r4.w], 1);
        cv[p3] = make_int2(c4.w, __float_as_int(v4.w));
    }
    if (tid == 0) {
        for (int i = nnz4 << 2; i < nnz; ++i) {
            int pos = atomicAdd(&cursor[rows[i]], 1);
            cv[pos] = make_int2(cols[i], __float_as_int(vals[i]));
        }
    }
}

// ===========================================================================
// gather SpMM over bf16 X: one wave per row, lane = dim (proven round-4)
// ===========================================================================
template <int WRITE_NORM>
__global__ void spmm_csr_kernel(const int* __restrict__ row_ptr,
                                const int2* __restrict__ cv,
                                const unsigned short* __restrict__ Xh,
                                unsigned short* __restrict__ Yh,
                                float* __restrict__ out,
                                float scale) {
    int wave = (blockIdx.x * blockDim.x + threadIdx.x) >> 6;
    if (wave >= NTOT) return;
    int lane = threadIdx.x & 63;
    int start = row_ptr[wave];
    int end   = row_ptr[wave + 1];
    float acc = 0.0f;
#pragma unroll 4
    for (int j = start; j < end; ++j) {
        int2 cvj = cv[j];
        float v  = __int_as_float(cvj.y);
        acc += v * bf2f(Xh[(size_t)cvj.x * EMB + lane]);
    }
    size_t o = (size_t)wave * EMB + lane;
    out[o] += scale * acc;
    if (WRITE_NORM) {
        float ss = acc * acc;
        ss += __shfl_xor(ss, 1);
        ss += __shfl_xor(ss, 2);
        ss += __shfl_xor(ss, 4);
        ss += __shfl_xor(ss, 8);
        ss += __shfl_xor(ss, 16);
        ss += __shfl_xor(ss, 32);
        float inv = 1.0f / (sqrtf(ss) + EPS);
        Yh[o] = f2bf(acc * inv);
    }
}

// ===========================================================================
// Last-resort scatter path (round-1 proven kernels)
// ===========================================================================

__global__ void scale_copy_kernel(const float* __restrict__ src,
                                  float* __restrict__ dst, float a, int n4) {
    int stride = gridDim.x * blockDim.x;
    for (int i = blockIdx.x * blockDim.x + threadIdx.x; i < n4; i += stride) {
        float4 v = reinterpret_cast<const float4*>(src)[i];
        v.x *= a; v.y *= a; v.z *= a; v.w *= a;
        reinterpret_cast<float4*>(dst)[i] = v;
    }
}

__global__ void normalize_kernel(const float* __restrict__ src,
                                 float* __restrict__ dst, int nrows) {
    int tid = blockIdx.x * blockDim.x + threadIdx.x;
    int row = tid >> 4;
    if (row >= nrows) return;
    int l = tid & 15;
    float4 v = reinterpret_cast<const float4*>(src)[(size_t)row * 16 + l];
    float ss = v.x * v.x + v.y * v.y + v.z * v.z + v.w * v.w;
    ss += __shfl_xor(ss, 1);
    ss += __shfl_xor(ss, 2);
    ss += __shfl_xor(ss, 4);
    ss += __shfl_xor(ss, 8);
    float inv = 1.0f / (sqrtf(ss) + EPS);
    v.x *= inv; v.y *= inv; v.z *= inv; v.w *= inv;
    reinterpret_cast<float4*>(dst)[(size_t)row * 16 + l] = v;
}

__global__ void spmm_scatter_kernel(const int* __restrict__ rows,
                                    const int* __restrict__ cols,
                                    const float* __restrict__ vals,
                                    const float* __restrict__ x,
                                    float* __restrict__ y, int nnz) {
    int lane = threadIdx.x & 63;
    int wave = (blockIdx.x * blockDim.x + threadIdx.x) >> 6;
    int nw   = (gridDim.x * blockDim.x) >> 6;
    for (int i = wave; i < nnz; i += nw) {
        int   r = rows[i];
        int   c = cols[i];
        float v = vals[i];
        atomicAdd(&y[(size_t)r * EMB + lane], v * x[(size_t)c * EMB + lane]);
    }
}

__global__ void axpy_kernel(const float* __restrict__ x,
                            float* __restrict__ out, float a, int n4) {
    int stride = gridDim.x * blockDim.x;
    for (int i = blockIdx.x * blockDim.x + threadIdx.x; i < n4; i += stride) {
        float4 v = reinterpret_cast<const float4*>(x)[i];
        float4 o = reinterpret_cast<float4*>(out)[i];
        o.x += a * v.x; o.y += a * v.y; o.z += a * v.z; o.w += a * v.w;
        reinterpret_cast<float4*>(out)[i] = o;
    }
}

// ===========================================================================

extern "C" void kernel_launch(void* const* d_in, const int* in_sizes, int n_in,
                              void* d_out, int out_size, void* d_ws, size_t ws_size,
                              hipStream_t stream) {
    const float* user_emb = (const float*)d_in[0];
    const float* item_emb = (const float*)d_in[1];
    const int*   rows     = (const int*)d_in[2];
    const int*   cols     = (const int*)d_in[3];
    const float* vals     = (const float*)d_in[4];
    const int    nnz      = in_sizes[2];

    float* out = (float*)d_out;
    const int TOTAL = NTOT * EMB;                  // 9,600,000
    const float layer_scale = (1.0f - GAMMA) / NLAYERS;
    const int SPMM_BLOCKS = (NTOT * 64 + 255) / 256;

    // ---- partitioned fast path layout ----
    // Xh | cv | row_ptr | rowcur | chunks | sb_count | sb_base | sb_cursor |
    // staging (Yh aliased: staging dead after sbfix, Yh first written later)
    size_t staging_elems = (size_t)nnz + 8 * NSB;
    size_t need_part = (size_t)TOTAL * 2                 // Xh
                     + (size_t)nnz * 8                   // cv
                     + (size_t)(NTOT + 1) * 4
                     + (size_t)NTOT * 4
                     + (size_t)NCHUNKS * 4
                     + (size_t)NSB * 4 * 3
                     + staging_elems * 8                 // staging (>= Yh)
                     + 4096;

    // ---- round-4 path layout ----
    size_t need_r4 = (size_t)TOTAL * 2 * 2 + (size_t)nnz * 8
                   + (size_t)(NTOT + 1) * 4 + (size_t)NTOT * 4
                   + (size_t)NCHUNKS * 4 + 1024;

    if (ws_size >= need_part) {
        char* p = (char*)d_ws;
        unsigned short* Xh = (unsigned short*)p;  p += (size_t)TOTAL * 2;
        int2* cv           = (int2*)p;            p += (size_t)nnz * 8;
        int*  row_ptr      = (int*)p;             p += (size_t)(NTOT + 1) * 4;
        int*  rowcur       = (int*)p;             p += (size_t)NTOT * 4;
        int*  chunks       = (int*)p;             p += (size_t)NCHUNKS * 4;
        int*  sb_count     = (int*)p;             p += (size_t)NSB * 4;
        int*  sb_base      = (int*)p;             p += (size_t)NSB * 4;
        int*  sb_cursor    = (int*)p;             p += (size_t)NSB * 4;
        p = (char*)(((uintptr_t)p + 15) & ~(uintptr_t)15);
        int2* staging      = (int2*)p;
        unsigned short* Yh = (unsigned short*)p;  // alias (staging dead by then)

        init_kernel<<<(NTOT * 16 + 255) / 256, 256, 0, stream>>>(
            user_emb, item_emb, Xh, out);

        hipMemsetAsync(rowcur, 0, (size_t)NTOT * 4, stream);   // counts
        hist4_kernel<<<2048, 256, 0, stream>>>(rows, rowcur, nnz);
        sbcount_kernel<<<NSB, 64, 0, stream>>>(rowcur, sb_count);
        sbscan_kernel<<<1, 64, 0, stream>>>(sb_count, sb_base, sb_cursor);
        scan_sums_kernel<<<NCHUNKS, SCAN_CHUNK, 0, stream>>>(rowcur, chunks);
        scan_offsets_kernel<<<1, 64, 0, stream>>>(chunks, row_ptr);
        scan_write_kernel<<<NCHUNKS, SCAN_CHUNK, 0, stream>>>(rowcur, chunks,
                                                              row_ptr, rowcur);
        partition_kernel<<<PBLOCKS, 256, 0, stream>>>(rows, cols, vals,
                                                      sb_cursor, staging, nnz);
        sbfix_kernel<<<NSB, 256, 0, stream>>>(staging, sb_base, sb_cursor,
                                              rowcur, cv);

        spmm_csr_kernel<1><<<SPMM_BLOCKS, 256, 0, stream>>>(
            row_ptr, cv, Xh, Yh, out, layer_scale);
        spmm_csr_kernel<1><<<SPMM_BLOCKS, 256, 0, stream>>>(
            row_ptr, cv, Yh, Xh, out, layer_scale);
        spmm_csr_kernel<0><<<SPMM_BLOCKS, 256, 0, stream>>>(
            row_ptr, cv, Xh, Yh, out, layer_scale);
        return;
    }

    if (ws_size >= need_r4) {
        char* p = (char*)d_ws;
        unsigned short* Xh = (unsigned short*)p;  p += (size_t)TOTAL * 2;
        unsigned short* Yh = (unsigned short*)p;  p += (size_t)TOTAL * 2;
        int2* cv           = (int2*)p;            p += (size_t)nnz * 8;
        int*  row_ptr      = (int*)p;             p += (size_t)(NTOT + 1) * 4;
        int*  cursor       = (int*)p;             p += (size_t)NTOT * 4;
        int*  chunks       = (int*)p;

        init_kernel<<<(NTOT * 16 + 255) / 256, 256, 0, stream>>>(
            user_emb, item_emb, Xh, out);
        hipMemsetAsync(cursor, 0, (size_t)NTOT * 4, stream);
        hist4_kernel<<<2048, 256, 0, stream>>>(rows, cursor, nnz);
        scan_sums_kernel<<<NCHUNKS, SCAN_CHUNK, 0, stream>>>(cursor, chunks);
        scan_offsets_kernel<<<1, 64, 0, stream>>>(chunks, row_ptr);
        scan_write_kernel<<<NCHUNKS, SCAN_CHUNK, 0, stream>>>(cursor, chunks,
                                                              row_ptr, cursor);
        build_kernel<<<2048, 256, 0, stream>>>(rows, cols, vals, cursor, cv, nnz);

        spmm_csr_kernel<1><<<SPMM_BLOCKS, 256, 0, stream>>>(
            row_ptr, cv, Xh, Yh, out, layer_scale);
        spmm_csr_kernel<1><<<SPMM_BLOCKS, 256, 0, stream>>>(
            row_ptr, cv, Yh, Xh, out, layer_scale);
        spmm_csr_kernel<0><<<SPMM_BLOCKS, 256, 0, stream>>>(
            row_ptr, cv, Xh, Yh, out, layer_scale);
        return;
    }

    // ---- last resort: round-1 scatter path ----
    float* A = (float*)d_ws;
    float* B = A + (size_t)TOTAL;
    const int T4 = TOTAL / 4;

    scale_copy_kernel<<<2048, 256, 0, stream>>>(user_emb, out, GAMMA,
                                                USER_NUM * EMB / 4);
    scale_copy_kernel<<<2048, 256, 0, stream>>>(item_emb, out + (size_t)USER_NUM * EMB,
                                                GAMMA, ITEM_NUM * EMB / 4);
    normalize_kernel<<<(USER_NUM * 16 + 255) / 256, 256, 0, stream>>>(
        user_emb, A, USER_NUM);
    normalize_kernel<<<(ITEM_NUM * 16 + 255) / 256, 256, 0, stream>>>(
        item_emb, A + (size_t)USER_NUM * EMB, ITEM_NUM);

    for (int layer = 0; layer < NLAYERS; ++layer) {
        if (layer > 0)
            normalize_kernel<<<(NTOT * 16 + 255) / 256, 256, 0, stream>>>(B, A, NTOT);
        hipMemsetAsync(B, 0, (size_t)TOTAL * sizeof(float), stream);
        spmm_scatter_kernel<<<8192, 256, 0, stream>>>(rows, cols, vals, A, B, nnz);
        axpy_kernel<<<2048, 256, 0, stream>>>(B, out, layer_scale, T4);
    }
}

// Round 6
// 1928.555 us; speedup vs baseline: 1.3326x; 1.3326x over previous
//
#include <hip/hip_runtime.h>

#define USER_NUM 100000
#define ITEM_NUM 50000
#define NTOT     (USER_NUM + ITEM_NUM)
#define EMB      64
#define GAMMA    0.5f
#define NLAYERS  3
#define EPS      1e-12f

// column segmentation: 6 segments of 25000 X-rows (3.2 MB bf16 each < 4 MB L2)
#define NSEG     6
#define SEGSZ    25000
#define NKEYS    (NSEG * NTOT)                     // 900000
#define NC1      ((NKEYS + 255) / 256)             // 3516
#define NC2      ((NC1 + 255) / 256)               // 14

// ---- bf16 helpers (explicit RNE, bit-level) ----
__device__ __forceinline__ unsigned short f2bf(float f) {
    unsigned u = __float_as_uint(f);
    u = (u + 0x7FFFu + ((u >> 16) & 1u)) >> 16;
    return (unsigned short)u;
}
__device__ __forceinline__ float bf2f(unsigned short h) {
    return __uint_as_float((unsigned)h << 16);
}

// ===========================================================================
// init: Xh = bf16(normalize(concat(user,item))), out = GAMMA * concat(...)
// ===========================================================================
__global__ void init_kernel(const float* __restrict__ user_emb,
                            const float* __restrict__ item_emb,
                            unsigned short* __restrict__ Xh,
                            float* __restrict__ out) {
    int tid = blockIdx.x * blockDim.x + threadIdx.x;
    int row = tid >> 4;
    if (row >= NTOT) return;
    int l = tid & 15;
    const float* src = (row < USER_NUM)
        ? user_emb + (size_t)row * EMB
        : item_emb + (size_t)(row - USER_NUM) * EMB;
    float4 v = reinterpret_cast<const float4*>(src)[l];
    float4 o = v; o.x *= GAMMA; o.y *= GAMMA; o.z *= GAMMA; o.w *= GAMMA;
    reinterpret_cast<float4*>(out)[(size_t)row * 16 + l] = o;
    float ss = v.x * v.x + v.y * v.y + v.z * v.z + v.w * v.w;
    ss += __shfl_xor(ss, 1);
    ss += __shfl_xor(ss, 2);
    ss += __shfl_xor(ss, 4);
    ss += __shfl_xor(ss, 8);
    float inv = 1.0f / (sqrtf(ss) + EPS);
    ushort4 h;
    h.x = f2bf(v.x * inv); h.y = f2bf(v.y * inv);
    h.z = f2bf(v.z * inv); h.w = f2bf(v.w * inv);
    reinterpret_cast<ushort4*>(Xh)[(size_t)row * 16 + l] = h;
}

// ===========================================================================
// histogram over segmented keys: key = (col/SEGSZ)*NTOT + row
// ===========================================================================
__global__ void hist4_kernel(const int* __restrict__ rows,
                             const int* __restrict__ cols,
                             int* __restrict__ counts, int nnz) {
    int tid = blockIdx.x * blockDim.x + threadIdx.x;
    int stride = gridDim.x * blockDim.x;
    int nnz4 = nnz >> 2;
    for (int i = tid; i < nnz4; i += stride) {
        int4 r4 = reinterpret_cast<const int4*>(rows)[i];
        int4 c4 = reinterpret_cast<const int4*>(cols)[i];
        atomicAdd(&counts[(c4.x / SEGSZ) * NTOT + r4.x], 1);
        atomicAdd(&counts[(c4.y / SEGSZ) * NTOT + r4.y], 1);
        atomicAdd(&counts[(c4.z / SEGSZ) * NTOT + r4.z], 1);
        atomicAdd(&counts[(c4.w / SEGSZ) * NTOT + r4.w], 1);
    }
    if (tid == 0)
        for (int i = nnz4 << 2; i < nnz; ++i)
            atomicAdd(&counts[(cols[i] / SEGSZ) * NTOT + rows[i]], 1);
}

// ===========================================================================
// 3-level hierarchical exclusive scan over NKEYS counts
// ===========================================================================
__global__ void sum256_kernel(const int* __restrict__ in,
                              int* __restrict__ out, int n) {
    __shared__ int s[256];
    int idx = blockIdx.x * 256 + threadIdx.x;
    s[threadIdx.x] = (idx < n) ? in[idx] : 0;
    __syncthreads();
    for (int off = 128; off > 0; off >>= 1) {
        if (threadIdx.x < off) s[threadIdx.x] += s[threadIdx.x + off];
        __syncthreads();
    }
    if (threadIdx.x == 0) out[blockIdx.x] = s[0];
}

__global__ void exscan_small_kernel(int* __restrict__ buf, int n,
                                    int* __restrict__ tail) {
    if (threadIdx.x == 0 && blockIdx.x == 0) {
        int run = 0;
        for (int b = 0; b < n; ++b) {
            int t = buf[b];
            buf[b] = run;
            run += t;
        }
        if (tail) *tail = run;   // == nnz
    }
}

// in-place: data[idx] = exclusive-scan-within-chunk + offs[chunk]
__global__ void scanw_mid_kernel(int* __restrict__ data,
                                 const int* __restrict__ offs, int n) {
    __shared__ int temp[256];
    int idx = blockIdx.x * 256 + threadIdx.x;
    int v = (idx < n) ? data[idx] : 0;
    temp[threadIdx.x] = v;
    __syncthreads();
    for (int off = 1; off < 256; off <<= 1) {
        int t = (threadIdx.x >= off) ? temp[threadIdx.x - off] : 0;
        __syncthreads();
        temp[threadIdx.x] += t;
        __syncthreads();
    }
    if (idx < n) data[idx] = temp[threadIdx.x] - v + offs[blockIdx.x];
}

// counts -> key_ptr (exclusive) and cursor (copy); counts overwritten in place
__global__ void scanw_final_kernel(int* __restrict__ counts_cursor,
                                   const int* __restrict__ offs,
                                   int* __restrict__ key_ptr, int n) {
    __shared__ int temp[256];
    int idx = blockIdx.x * 256 + threadIdx.x;
    int v = (idx < n) ? counts_cursor[idx] : 0;
    temp[threadIdx.x] = v;
    __syncthreads();
    for (int off = 1; off < 256; off <<= 1) {
        int t = (threadIdx.x >= off) ? temp[threadIdx.x - off] : 0;
        __syncthreads();
        temp[threadIdx.x] += t;
        __syncthreads();
    }
    if (idx < n) {
        int excl = temp[threadIdx.x] - v + offs[blockIdx.x];
        key_ptr[idx]       = excl;
        counts_cursor[idx] = excl;
    }
}

// ===========================================================================
// single-pass segmented-CSR build (proven round-4 structure, segmented key).
// Random 8B writes: write-line-amplification-bound (~494 MB), but faster than
// every buffered/binned variant tried (rounds 3 & 5 post-mortems).
// ===========================================================================
__global__ void build_kernel(const int* __restrict__ rows,
                             const int* __restrict__ cols,
                             const float* __restrict__ vals,
                             int* __restrict__ cursor,
                             int2* __restrict__ cv, int nnz) {
    int tid = blockIdx.x * blockDim.x + threadIdx.x;
    int stride = gridDim.x * blockDim.x;
    int nnz4 = nnz >> 2;
    for (int i = tid; i < nnz4; i += stride) {
        int4   r4 = reinterpret_cast<const int4*>(rows)[i];
        int4   c4 = reinterpret_cast<const int4*>(cols)[i];
        float4 v4 = reinterpret_cast<const float4*>(vals)[i];
        int p0 = atomicAdd(&cursor[(c4.x / SEGSZ) * NTOT + r4.x], 1);
        cv[p0] = make_int2(c4.x, __float_as_int(v4.x));
        int p1 = atomicAdd(&cursor[(c4.y / SEGSZ) * NTOT + r4.y], 1);
        cv[p1] = make_int2(c4.y, __float_as_int(v4.y));
        int p2 = atomicAdd(&cursor[(c4.z / SEGSZ) * NTOT + r4.z], 1);
        cv[p2] = make_int2(c4.z, __float_as_int(v4.z));
        int p3 = atomicAdd(&cursor[(c4.w / SEGSZ) * NTOT + r4.w], 1);
        cv[p3] = make_int2(c4.w, __float_as_int(v4.w));
    }
    if (tid == 0) {
        for (int i = nnz4 << 2; i < nnz; ++i) {
            int pos = atomicAdd(&cursor[(cols[i] / SEGSZ) * NTOT + rows[i]], 1);
            cv[pos] = make_int2(cols[i], __float_as_int(vals[i]));
        }
    }
}

// ===========================================================================
// segment-pass gather SpMM: one wave per row, lane = dim. Pass s gathers only
// from X-rows [s*SEGSZ, (s+1)*SEGSZ) -> 3.2 MB working set, L2-resident.
// FIRST: acc=0 (skip y read). LAST: fuse out-accumulate (+normalize if WN).
// ===========================================================================
template <int FIRST, int LAST, int WN>
__global__ void spmm_seg_kernel(const int* __restrict__ kptr,
                                const int2* __restrict__ cv,
                                const unsigned short* __restrict__ Xh,
                                unsigned short* __restrict__ Yh,
                                float* __restrict__ y32,
                                float* __restrict__ out,
                                float scale) {
    int wave = (blockIdx.x * blockDim.x + threadIdx.x) >> 6;
    if (wave >= NTOT) return;
    int lane = threadIdx.x & 63;
    int start = kptr[wave];
    int end   = kptr[wave + 1];
    size_t o = (size_t)wave * EMB + lane;
    float acc = FIRST ? 0.0f : y32[o];
#pragma unroll 4
    for (int j = start; j < end; ++j) {
        int2 cvj = cv[j];
        acc += __int_as_float(cvj.y) * bf2f(Xh[(size_t)cvj.x * EMB + lane]);
    }
    if (!LAST) {
        y32[o] = acc;
        return;
    }
    out[o] += scale * acc;
    if (WN) {
        float ss = acc * acc;
        ss += __shfl_xor(ss, 1);
        ss += __shfl_xor(ss, 2);
        ss += __shfl_xor(ss, 4);
        ss += __shfl_xor(ss, 8);
        ss += __shfl_xor(ss, 16);
        ss += __shfl_xor(ss, 32);
        float inv = 1.0f / (sqrtf(ss) + EPS);
        Yh[o] = f2bf(acc * inv);
    }
}

// ===========================================================================
// Last-resort scatter path (round-1 proven kernels)
// ===========================================================================

__global__ void scale_copy_kernel(const float* __restrict__ src,
                                  float* __restrict__ dst, float a, int n4) {
    int stride = gridDim.x * blockDim.x;
    for (int i = blockIdx.x * blockDim.x + threadIdx.x; i < n4; i += stride) {
        float4 v = reinterpret_cast<const float4*>(src)[i];
        v.x *= a; v.y *= a; v.z *= a; v.w *= a;
        reinterpret_cast<float4*>(dst)[i] = v;
    }
}

__global__ void normalize_kernel(const float* __restrict__ src,
                                 float* __restrict__ dst, int nrows) {
    int tid = blockIdx.x * blockDim.x + threadIdx.x;
    int row = tid >> 4;
    if (row >= nrows) return;
    int l = tid & 15;
    float4 v = reinterpret_cast<const float4*>(src)[(size_t)row * 16 + l];
    float ss = v.x * v.x + v.y * v.y + v.z * v.z + v.w * v.w;
    ss += __shfl_xor(ss, 1);
    ss += __shfl_xor(ss, 2);
    ss += __shfl_xor(ss, 4);
    ss += __shfl_xor(ss, 8);
    float inv = 1.0f / (sqrtf(ss) + EPS);
    v.x *= inv; v.y *= inv; v.z *= inv; v.w *= inv;
    reinterpret_cast<float4*>(dst)[(size_t)row * 16 + l] = v;
}

__global__ void spmm_scatter_kernel(const int* __restrict__ rows,
                                    const int* __restrict__ cols,
                                    const float* __restrict__ vals,
                                    const float* __restrict__ x,
                                    float* __restrict__ y, int nnz) {
    int lane = threadIdx.x & 63;
    int wave = (blockIdx.x * blockDim.x + threadIdx.x) >> 6;
    int nw   = (gridDim.x * blockDim.x) >> 6;
    for (int i = wave; i < nnz; i += nw) {
        int   r = rows[i];
        int   c = cols[i];
        float v = vals[i];
        atomicAdd(&y[(size_t)r * EMB + lane], v * x[(size_t)c * EMB + lane]);
    }
}

__global__ void axpy_kernel(const float* __restrict__ x,
                            float* __restrict__ out, float a, int n4) {
    int stride = gridDim.x * blockDim.x;
    for (int i = blockIdx.x * blockDim.x + threadIdx.x; i < n4; i += stride) {
        float4 v = reinterpret_cast<const float4*>(x)[i];
        float4 o = reinterpret_cast<float4*>(out)[i];
        o.x += a * v.x; o.y += a * v.y; o.z += a * v.z; o.w += a * v.w;
        reinterpret_cast<float4*>(out)[i] = o;
    }
}

// ===========================================================================

extern "C" void kernel_launch(void* const* d_in, const int* in_sizes, int n_in,
                              void* d_out, int out_size, void* d_ws, size_t ws_size,
                              hipStream_t stream) {
    const float* user_emb = (const float*)d_in[0];
    const float* item_emb = (const float*)d_in[1];
    const int*   rows     = (const int*)d_in[2];
    const int*   cols     = (const int*)d_in[3];
    const float* vals     = (const float*)d_in[4];
    const int    nnz      = in_sizes[2];

    float* out = (float*)d_out;
    const int TOTAL = NTOT * EMB;                  // 9,600,000
    const float layer_scale = (1.0f - GAMMA) / NLAYERS;
    const int SPMM_BLOCKS = (NTOT * 64 + 255) / 256;   // 37500

    // ---- segmented-CSR layout ----
    // Xh | Yh | y32 | cv | key_ptr | cursor | cs1 | cs2
    size_t need = (size_t)TOTAL * 2 * 2            // Xh, Yh
                + (size_t)TOTAL * 4                // y32
                + (size_t)nnz * 8                  // cv
                + (size_t)(NKEYS + 1) * 4          // key_ptr
                + (size_t)NKEYS * 4                // cursor (=counts)
                + (size_t)NC1 * 4 + (size_t)NC2 * 4
                + 1024;

    if (ws_size >= need) {
        char* p = (char*)d_ws;
        unsigned short* Xh = (unsigned short*)p;  p += (size_t)TOTAL * 2;
        unsigned short* Yh = (unsigned short*)p;  p += (size_t)TOTAL * 2;
        float* y32         = (float*)p;           p += (size_t)TOTAL * 4;
        int2*  cv          = (int2*)p;            p += (size_t)nnz * 8;
        int*   key_ptr     = (int*)p;             p += (size_t)(NKEYS + 1) * 4;
        int*   cursor      = (int*)p;             p += (size_t)NKEYS * 4;
        int*   cs1         = (int*)p;             p += (size_t)NC1 * 4;
        int*   cs2         = (int*)p;

        init_kernel<<<(NTOT * 16 + 255) / 256, 256, 0, stream>>>(
            user_emb, item_emb, Xh, out);

        // segmented-CSR build: hist -> 3-level scan -> scatter
        hipMemsetAsync(cursor, 0, (size_t)NKEYS * 4, stream);
        hist4_kernel<<<2048, 256, 0, stream>>>(rows, cols, cursor, nnz);
        sum256_kernel<<<NC1, 256, 0, stream>>>(cursor, cs1, NKEYS);
        sum256_kernel<<<NC2, 256, 0, stream>>>(cs1, cs2, NC1);
        exscan_small_kernel<<<1, 64, 0, stream>>>(cs2, NC2, key_ptr + NKEYS);
        scanw_mid_kernel<<<NC2, 256, 0, stream>>>(cs1, cs2, NC1);
        scanw_final_kernel<<<NC1, 256, 0, stream>>>(cursor, cs1, key_ptr, NKEYS);
        build_kernel<<<2048, 256, 0, stream>>>(rows, cols, vals, cursor, cv, nnz);

        // 3 layers x NSEG segment passes (L2-resident gathers per pass)
        for (int layer = 0; layer < NLAYERS; ++layer) {
            const unsigned short* Xc = (layer & 1) ? Yh : Xh;
            unsigned short*       Yn = (layer & 1) ? Xh : Yh;
            for (int s = 0; s < NSEG; ++s) {
                const int* kp = key_ptr + (size_t)s * NTOT;
                if (s == 0) {
                    spmm_seg_kernel<1, 0, 0><<<SPMM_BLOCKS, 256, 0, stream>>>(
                        kp, cv, Xc, Yn, y32, out, layer_scale);
                } else if (s < NSEG - 1) {
                    spmm_seg_kernel<0, 0, 0><<<SPMM_BLOCKS, 256, 0, stream>>>(
                        kp, cv, Xc, Yn, y32, out, layer_scale);
                } else if (layer < NLAYERS - 1) {
                    spmm_seg_kernel<0, 1, 1><<<SPMM_BLOCKS, 256, 0, stream>>>(
                        kp, cv, Xc, Yn, y32, out, layer_scale);
                } else {
                    spmm_seg_kernel<0, 1, 0><<<SPMM_BLOCKS, 256, 0, stream>>>(
                        kp, cv, Xc, Yn, y32, out, layer_scale);
                }
            }
        }
        return;
    }

    // ---- last resort: round-1 scatter path (needs 76.8 MB) ----
    float* A = (float*)d_ws;
    float* B = A + (size_t)TOTAL;
    const int T4 = TOTAL / 4;

    scale_copy_kernel<<<2048, 256, 0, stream>>>(user_emb, out, GAMMA,
                                                USER_NUM * EMB / 4);
    scale_copy_kernel<<<2048, 256, 0, stream>>>(item_emb, out + (size_t)USER_NUM * EMB,
                                                GAMMA, ITEM_NUM * EMB / 4);
    normalize_kernel<<<(USER_NUM * 16 + 255) / 256, 256, 0, stream>>>(
        user_emb, A, USER_NUM);
    normalize_kernel<<<(ITEM_NUM * 16 + 255) / 256, 256, 0, stream>>>(
        item_emb, A + (size_t)USER_NUM * EMB, ITEM_NUM);

    for (int layer = 0; layer < NLAYERS; ++layer) {
        if (layer > 0)
            normalize_kernel<<<(NTOT * 16 + 255) / 256, 256, 0, stream>>>(B, A, NTOT);
        hipMemsetAsync(B, 0, (size_t)TOTAL * sizeof(float), stream);
        spmm_scatter_kernel<<<8192, 256, 0, stream>>>(rows, cols, vals, A, B, nnz);
        axpy_kernel<<<2048, 256, 0, stream>>>(B, out, layer_scale, T4);
    }
}

// Round 7
// 1225.636 us; speedup vs baseline: 2.0968x; 1.5735x over previous
//
#include <hip/hip_runtime.h>

#define USER_NUM 100000
#define ITEM_NUM 50000
#define NTOT     (USER_NUM + ITEM_NUM)
#define EMB      64
#define GAMMA    0.5f
#define NLAYERS  3
#define EPS      1e-12f

#define SCAN_CHUNK 256
#define NCHUNKS    ((NTOT + SCAN_CHUNK - 1) / SCAN_CHUNK)   // 586

// ---- bf16 helpers (explicit RNE, bit-level) ----
__device__ __forceinline__ unsigned short f2bf(float f) {
    unsigned u = __float_as_uint(f);
    u = (u + 0x7FFFu + ((u >> 16) & 1u)) >> 16;
    return (unsigned short)u;
}
__device__ __forceinline__ float bf2f(unsigned short h) {
    return __uint_as_float((unsigned)h << 16);
}

// ===========================================================================
// init: Xh = bf16(normalize(concat(user,item))), out = GAMMA * concat(...)
// ===========================================================================
__global__ void init_kernel(const float* __restrict__ user_emb,
                            const float* __restrict__ item_emb,
                            unsigned short* __restrict__ Xh,
                            float* __restrict__ out) {
    int tid = blockIdx.x * blockDim.x + threadIdx.x;
    int row = tid >> 4;
    if (row >= NTOT) return;
    int l = tid & 15;
    const float* src = (row < USER_NUM)
        ? user_emb + (size_t)row * EMB
        : item_emb + (size_t)(row - USER_NUM) * EMB;
    float4 v = reinterpret_cast<const float4*>(src)[l];
    float4 o = v; o.x *= GAMMA; o.y *= GAMMA; o.z *= GAMMA; o.w *= GAMMA;
    reinterpret_cast<float4*>(out)[(size_t)row * 16 + l] = o;
    float ss = v.x * v.x + v.y * v.y + v.z * v.z + v.w * v.w;
    ss += __shfl_xor(ss, 1);
    ss += __shfl_xor(ss, 2);
    ss += __shfl_xor(ss, 4);
    ss += __shfl_xor(ss, 8);
    float inv = 1.0f / (sqrtf(ss) + EPS);
    ushort4 h;
    h.x = f2bf(v.x * inv); h.y = f2bf(v.y * inv);
    h.z = f2bf(v.z * inv); h.w = f2bf(v.w * inv);
    reinterpret_cast<ushort4*>(Xh)[(size_t)row * 16 + l] = h;
}

// ===========================================================================
// histogram (int4-vectorized index reads)
// ===========================================================================
__global__ void hist4_kernel(const int* __restrict__ rows,
                             int* __restrict__ counts, int nnz) {
    int tid = blockIdx.x * blockDim.x + threadIdx.x;
    int stride = gridDim.x * blockDim.x;
    int nnz4 = nnz >> 2;
    for (int i = tid; i < nnz4; i += stride) {
        int4 r4 = reinterpret_cast<const int4*>(rows)[i];
        atomicAdd(&counts[r4.x], 1);
        atomicAdd(&counts[r4.y], 1);
        atomicAdd(&counts[r4.z], 1);
        atomicAdd(&counts[r4.w], 1);
    }
    if (tid == 0)
        for (int i = nnz4 << 2; i < nnz; ++i) atomicAdd(&counts[rows[i]], 1);
}

// ===========================================================================
// 3-step exclusive scan of per-row counts -> row_ptr (and cursor copy)
// ===========================================================================
__global__ void scan_sums_kernel(const int* __restrict__ counts,
                                 int* __restrict__ chunk_sums) {
    __shared__ int sdata[SCAN_CHUNK];
    int idx = blockIdx.x * SCAN_CHUNK + threadIdx.x;
    int v = (idx < NTOT) ? counts[idx] : 0;
    sdata[threadIdx.x] = v;
    __syncthreads();
    for (int off = SCAN_CHUNK / 2; off > 0; off >>= 1) {
        if (threadIdx.x < off) sdata[threadIdx.x] += sdata[threadIdx.x + off];
        __syncthreads();
    }
    if (threadIdx.x == 0) chunk_sums[blockIdx.x] = sdata[0];
}

__global__ void scan_offsets_kernel(int* __restrict__ chunk_sums,
                                    int* __restrict__ row_ptr) {
    if (threadIdx.x == 0 && blockIdx.x == 0) {
        int running = 0;
        for (int b = 0; b < NCHUNKS; ++b) {
            int t = chunk_sums[b];
            chunk_sums[b] = running;
            running += t;
        }
        row_ptr[NTOT] = running;
    }
}

__global__ void scan_write_kernel(const int* __restrict__ counts,
                                  const int* __restrict__ chunk_sums,
                                  int* __restrict__ row_ptr,
                                  int* __restrict__ cursor) {
    __shared__ int temp[SCAN_CHUNK];
    int idx = blockIdx.x * SCAN_CHUNK + threadIdx.x;
    int v = (idx < NTOT) ? counts[idx] : 0;
    temp[threadIdx.x] = v;
    __syncthreads();
    for (int off = 1; off < SCAN_CHUNK; off <<= 1) {
        int t = (threadIdx.x >= off) ? temp[threadIdx.x - off] : 0;
        __syncthreads();
        temp[threadIdx.x] += t;
        __syncthreads();
    }
    if (idx < NTOT) {
        int excl = temp[threadIdx.x] - v + chunk_sums[blockIdx.x];
        row_ptr[idx] = excl;
        cursor[idx]  = excl;
    }
}

// ===========================================================================
// single-pass CSR build — round-2 scalar form (measured faster than int4
// variant: ~440 vs ~525 µs). Random 8B writes; line-transaction bound.
// ===========================================================================
__global__ void build_kernel(const int* __restrict__ rows,
                             const int* __restrict__ cols,
                             const float* __restrict__ vals,
                             int* __restrict__ cursor,
                             int2* __restrict__ cv, int nnz) {
    int stride = gridDim.x * blockDim.x;
    for (int i = blockIdx.x * blockDim.x + threadIdx.x; i < nnz; i += stride) {
        int r = rows[i];
        int pos = atomicAdd(&cursor[r], 1);
        cv[pos] = make_int2(cols[i], __float_as_int(vals[i]));
    }
}

// ===========================================================================
// gather SpMM over bf16 X: one wave per row, lane = dim.
// Row bounds hoisted to SGPRs (readfirstlane) so cv batch loads go through
// the scalar K$ path (s_load) and the 8 gathers per batch issue back-to-back
// with no interleaved VMEM cv loads -> deeper MLP per wave.
// ===========================================================================
template <int WRITE_NORM>
__global__ void spmm_csr_kernel(const int* __restrict__ row_ptr,
                                const int2* __restrict__ cv,
                                const unsigned short* __restrict__ Xh,
                                unsigned short* __restrict__ Yh,
                                float* __restrict__ out,
                                float scale) {
    int wave = (blockIdx.x * blockDim.x + threadIdx.x) >> 6;
    if (wave >= NTOT) return;
    int lane = threadIdx.x & 63;
    int start = __builtin_amdgcn_readfirstlane(row_ptr[wave]);
    int end   = __builtin_amdgcn_readfirstlane(row_ptr[wave + 1]);
    int n = end - start;
    const int2* p = cv + start;

    float acc = 0.0f;
    int k = 0;
    for (; k + 8 <= n; k += 8) {
        int2 c0 = p[k + 0], c1 = p[k + 1], c2 = p[k + 2], c3 = p[k + 3];
        int2 c4 = p[k + 4], c5 = p[k + 5], c6 = p[k + 6], c7 = p[k + 7];
        float x0 = bf2f(Xh[(size_t)c0.x * EMB + lane]);
        float x1 = bf2f(Xh[(size_t)c1.x * EMB + lane]);
        float x2 = bf2f(Xh[(size_t)c2.x * EMB + lane]);
        float x3 = bf2f(Xh[(size_t)c3.x * EMB + lane]);
        float x4 = bf2f(Xh[(size_t)c4.x * EMB + lane]);
        float x5 = bf2f(Xh[(size_t)c5.x * EMB + lane]);
        float x6 = bf2f(Xh[(size_t)c6.x * EMB + lane]);
        float x7 = bf2f(Xh[(size_t)c7.x * EMB + lane]);
        acc += __int_as_float(c0.y) * x0;
        acc += __int_as_float(c1.y) * x1;
        acc += __int_as_float(c2.y) * x2;
        acc += __int_as_float(c3.y) * x3;
        acc += __int_as_float(c4.y) * x4;
        acc += __int_as_float(c5.y) * x5;
        acc += __int_as_float(c6.y) * x6;
        acc += __int_as_float(c7.y) * x7;
    }
    for (; k + 4 <= n; k += 4) {
        int2 c0 = p[k + 0], c1 = p[k + 1], c2 = p[k + 2], c3 = p[k + 3];
        float x0 = bf2f(Xh[(size_t)c0.x * EMB + lane]);
        float x1 = bf2f(Xh[(size_t)c1.x * EMB + lane]);
        float x2 = bf2f(Xh[(size_t)c2.x * EMB + lane]);
        float x3 = bf2f(Xh[(size_t)c3.x * EMB + lane]);
        acc += __int_as_float(c0.y) * x0;
        acc += __int_as_float(c1.y) * x1;
        acc += __int_as_float(c2.y) * x2;
        acc += __int_as_float(c3.y) * x3;
    }
    for (; k < n; ++k) {
        int2 c0 = p[k];
        acc += __int_as_float(c0.y) * bf2f(Xh[(size_t)c0.x * EMB + lane]);
    }

    size_t o = (size_t)wave * EMB + lane;
    out[o] += scale * acc;
    if (WRITE_NORM) {
        float ss = acc * acc;
        ss += __shfl_xor(ss, 1);
        ss += __shfl_xor(ss, 2);
        ss += __shfl_xor(ss, 4);
        ss += __shfl_xor(ss, 8);
        ss += __shfl_xor(ss, 16);
        ss += __shfl_xor(ss, 32);
        float inv = 1.0f / (sqrtf(ss) + EPS);
        Yh[o] = f2bf(acc * inv);
    }
}

// ===========================================================================
// Last-resort scatter path (round-1 proven kernels)
// ===========================================================================

__global__ void scale_copy_kernel(const float* __restrict__ src,
                                  float* __restrict__ dst, float a, int n4) {
    int stride = gridDim.x * blockDim.x;
    for (int i = blockIdx.x * blockDim.x + threadIdx.x; i < n4; i += stride) {
        float4 v = reinterpret_cast<const float4*>(src)[i];
        v.x *= a; v.y *= a; v.z *= a; v.w *= a;
        reinterpret_cast<float4*>(dst)[i] = v;
    }
}

__global__ void normalize_kernel(const float* __restrict__ src,
                                 float* __restrict__ dst, int nrows) {
    int tid = blockIdx.x * blockDim.x + threadIdx.x;
    int row = tid >> 4;
    if (row >= nrows) return;
    int l = tid & 15;
    float4 v = reinterpret_cast<const float4*>(src)[(size_t)row * 16 + l];
    float ss = v.x * v.x + v.y * v.y + v.z * v.z + v.w * v.w;
    ss += __shfl_xor(ss, 1);
    ss += __shfl_xor(ss, 2);
    ss += __shfl_xor(ss, 4);
    ss += __shfl_xor(ss, 8);
    float inv = 1.0f / (sqrtf(ss) + EPS);
    v.x *= inv; v.y *= inv; v.z *= inv; v.w *= inv;
    reinterpret_cast<float4*>(dst)[(size_t)row * 16 + l] = v;
}

__global__ void spmm_scatter_kernel(const int* __restrict__ rows,
                                    const int* __restrict__ cols,
                                    const float* __restrict__ vals,
                                    const float* __restrict__ x,
                                    float* __restrict__ y, int nnz) {
    int lane = threadIdx.x & 63;
    int wave = (blockIdx.x * blockDim.x + threadIdx.x) >> 6;
    int nw   = (gridDim.x * blockDim.x) >> 6;
    for (int i = wave; i < nnz; i += nw) {
        int   r = rows[i];
        int   c = cols[i];
        float v = vals[i];
        atomicAdd(&y[(size_t)r * EMB + lane], v * x[(size_t)c * EMB + lane]);
    }
}

__global__ void axpy_kernel(const float* __restrict__ x,
                            float* __restrict__ out, float a, int n4) {
    int stride = gridDim.x * blockDim.x;
    for (int i = blockIdx.x * blockDim.x + threadIdx.x; i < n4; i += stride) {
        float4 v = reinterpret_cast<const float4*>(x)[i];
        float4 o = reinterpret_cast<float4*>(out)[i];
        o.x += a * v.x; o.y += a * v.y; o.z += a * v.z; o.w += a * v.w;
        reinterpret_cast<float4*>(out)[i] = o;
    }
}

// ===========================================================================

extern "C" void kernel_launch(void* const* d_in, const int* in_sizes, int n_in,
                              void* d_out, int out_size, void* d_ws, size_t ws_size,
                              hipStream_t stream) {
    const float* user_emb = (const float*)d_in[0];
    const float* item_emb = (const float*)d_in[1];
    const int*   rows     = (const int*)d_in[2];
    const int*   cols     = (const int*)d_in[3];
    const float* vals     = (const float*)d_in[4];
    const int    nnz      = in_sizes[2];

    float* out = (float*)d_out;
    const int TOTAL = NTOT * EMB;                  // 9,600,000
    const float layer_scale = (1.0f - GAMMA) / NLAYERS;
    const int SPMM_BLOCKS = (NTOT * 64 + 255) / 256;

    // ---- bf16 CSR path layout: Xh | Yh | cv | row_ptr | cursor | chunks ----
    size_t need = (size_t)TOTAL * 2 * 2            // Xh, Yh (bf16)
                + (size_t)nnz * 8                  // cv
                + (size_t)(NTOT + 1) * 4
                + (size_t)NTOT * 4
                + (size_t)NCHUNKS * 4
                + 1024;

    if (ws_size >= need) {
        char* p = (char*)d_ws;
        unsigned short* Xh = (unsigned short*)p;  p += (size_t)TOTAL * 2;
        unsigned short* Yh = (unsigned short*)p;  p += (size_t)TOTAL * 2;
        int2* cv           = (int2*)p;            p += (size_t)nnz * 8;
        int*  row_ptr      = (int*)p;             p += (size_t)(NTOT + 1) * 4;
        int*  cursor       = (int*)p;             p += (size_t)NTOT * 4;
        int*  chunks       = (int*)p;

        init_kernel<<<(NTOT * 16 + 255) / 256, 256, 0, stream>>>(
            user_emb, item_emb, Xh, out);

        hipMemsetAsync(cursor, 0, (size_t)NTOT * 4, stream);   // counts
        hist4_kernel<<<2048, 256, 0, stream>>>(rows, cursor, nnz);
        scan_sums_kernel<<<NCHUNKS, SCAN_CHUNK, 0, stream>>>(cursor, chunks);
        scan_offsets_kernel<<<1, 64, 0, stream>>>(chunks, row_ptr);
        scan_write_kernel<<<NCHUNKS, SCAN_CHUNK, 0, stream>>>(cursor, chunks,
                                                              row_ptr, cursor);
        build_kernel<<<4096, 256, 0, stream>>>(rows, cols, vals, cursor, cv, nnz);

        spmm_csr_kernel<1><<<SPMM_BLOCKS, 256, 0, stream>>>(
            row_ptr, cv, Xh, Yh, out, layer_scale);
        spmm_csr_kernel<1><<<SPMM_BLOCKS, 256, 0, stream>>>(
            row_ptr, cv, Yh, Xh, out, layer_scale);
        spmm_csr_kernel<0><<<SPMM_BLOCKS, 256, 0, stream>>>(
            row_ptr, cv, Xh, Yh, out, layer_scale);
        return;
    }

    // ---- last resort: round-1 scatter path (needs 76.8 MB) ----
    float* A = (float*)d_ws;
    float* B = A + (size_t)TOTAL;
    const int T4 = TOTAL / 4;

    scale_copy_kernel<<<2048, 256, 0, stream>>>(user_emb, out, GAMMA,
                                                USER_NUM * EMB / 4);
    scale_copy_kernel<<<2048, 256, 0, stream>>>(item_emb, out + (size_t)USER_NUM * EMB,
                                                GAMMA, ITEM_NUM * EMB / 4);
    normalize_kernel<<<(USER_NUM * 16 + 255) / 256, 256, 0, stream>>>(
        user_emb, A, USER_NUM);
    normalize_kernel<<<(ITEM_NUM * 16 + 255) / 256, 256, 0, stream>>>(
        item_emb, A + (size_t)USER_NUM * EMB, ITEM_NUM);

    for (int layer = 0; layer < NLAYERS; ++layer) {
        if (layer > 0)
            normalize_kernel<<<(NTOT * 16 + 255) / 256, 256, 0, stream>>>(B, A, NTOT);
        hipMemsetAsync(B, 0, (size_t)TOTAL * sizeof(float), stream);
        spmm_scatter_kernel<<<8192, 256, 0, stream>>>(rows, cols, vals, A, B, nnz);
        axpy_kernel<<<2048, 256, 0, stream>>>(B, out, layer_scale, T4);
    }
}